// Round 2
// baseline (681.436 us; speedup 1.0000x reference)
//
#include <hip/hip_runtime.h>
#include <hip/hip_bf16.h>
#include <math.h>

#define V_NODES 262144
#define NGRAPH  4096
#define FD      256
#define TSTEPS  2
#define GP      8      // graphs per k_steps block (wave per graph)
#define SB      512    // k_steps block size: 8 waves
#define RS      264    // padded LDS row stride (u16) — 528B = 33*16B, +4-bank skew
#define EWCAP   1536   // max nodes per GP-graph block (mean 512, sigma ~23)

typedef unsigned short u16;
typedef __attribute__((ext_vector_type(8))) short short8;
typedef __attribute__((ext_vector_type(4))) float f32x4;

__device__ __forceinline__ float bf2f(u16 u) {
  union { unsigned int i; float f; } x; x.i = ((unsigned int)u) << 16; return x.f;
}
__device__ __forceinline__ u16 f2bf(float f) {
  union { unsigned int i; float f; } x; x.f = f;
  unsigned int r = x.i + 0x7FFFu + ((x.i >> 16) & 1u);
  return (u16)(r >> 16);
}
__device__ __forceinline__ unsigned int pkbf(float a, float b) {
  return (unsigned int)f2bf(a) | ((unsigned int)f2bf(b) << 16);
}
__device__ __forceinline__ float softplus2(float x) {
  return fmaxf(x, 0.0f) + log1pf(__expf(-fabsf(x))) - 0.69314718056f;
}
__device__ __forceinline__ float dot8(const float4 x0, const float4 x1, const float* w) {
  float d = fmaf(x0.x, w[0], fmaf(x0.y, w[1], fmaf(x0.z, w[2], x0.w * w[3])));
  return fmaf(x1.x, w[4], fmaf(x1.y, w[5], fmaf(x1.z, w[6], fmaf(x1.w, w[7], d))));
}

// ---- K0: bounds + weight conversions + proj transpose (one launch)
__global__ __launch_bounds__(256) void k_prep(
    const int* __restrict__ seg, const float* __restrict__ w_ih,
    const float* __restrict__ w_hh, const float* __restrict__ proj_w,
    int* __restrict__ start, u16* __restrict__ wihbf, u16* __restrict__ whhbf,
    u16* __restrict__ whhlo, u16* __restrict__ pwtbf) {
  __shared__ float tl[32][33];
  const int b = blockIdx.x, tid = threadIdx.x;
  const int gtid = b * 256 + tid;  // 0..262143
  {
    const int v = gtid;
    const int s = seg[v];
    if (v == 0) {
      for (int g = 0; g <= s; ++g) start[g] = 0;
    } else {
      const int p = seg[v - 1];
      for (int g = p + 1; g <= s; ++g) start[g] = v;
    }
    if (v == V_NODES - 1)
      for (int g = s + 1; g <= NGRAPH; ++g) start[g] = V_NODES;
  }
  {
    const int nchunk = TSTEPS * 768 * FD / 4;  // 98304
    if (gtid < nchunk) {
      const float4 x = ((const float4*)w_ih)[gtid];
      uint2 u; u.x = pkbf(x.x, x.y); u.y = pkbf(x.z, x.w);
      ((uint2*)wihbf)[gtid] = u;
      const float4 y = ((const float4*)w_hh)[gtid];
      const u16 h0 = f2bf(y.x), h1 = f2bf(y.y), h2 = f2bf(y.z), h3 = f2bf(y.w);
      uint2 hi_, lo_;
      hi_.x = (unsigned)h0 | ((unsigned)h1 << 16);
      hi_.y = (unsigned)h2 | ((unsigned)h3 << 16);
      lo_.x = pkbf(y.x - bf2f(h0), y.y - bf2f(h1));
      lo_.y = pkbf(y.z - bf2f(h2), y.w - bf2f(h3));
      ((uint2*)whhbf)[gtid] = hi_;
      ((uint2*)whhlo)[gtid] = lo_;
    }
  }
  if (b < 2 * 64) {  // proj_w [k][n] -> bf16 [n][k]
    const int t = b >> 6, tile = b & 63, bx = tile & 7, by = tile >> 3;
    const int tx = tid & 31, ty = tid >> 5;  // 32 x 8
    const float* S = proj_w + (size_t)t * FD * FD;
    u16* D = pwtbf + (size_t)t * FD * FD;
#pragma unroll
    for (int i = 0; i < 32; i += 8)
      tl[ty + i][tx] = S[(size_t)(by * 32 + ty + i) * FD + bx * 32 + tx];
    __syncthreads();
#pragma unroll
    for (int i = 0; i < 32; i += 8)
      D[(size_t)(bx * 32 + ty + i) * FD + by * 32 + tx] = f2bf(tl[tx][ty + i]);
  }
}

// ---- K1: block per graph (4096 blocks): segsum -> gf, bf16 copy, logit dots.
// 2 rows in flight per half-wave; interleaved shfl butterflies.
__global__ __launch_bounds__(256) void k_pass1(
    const float* __restrict__ nf, const int* __restrict__ start,
    const float* __restrict__ logit_w, float* __restrict__ gf,
    u16* __restrict__ nbf, float* __restrict__ d0, float* __restrict__ d1) {
  __shared__ __align__(16) float redf[8][FD];
  const int g = blockIdx.x, tid = threadIdx.x;
  const int h = tid >> 5, sl = tid & 31;  // 8 half-waves, 8 feats/lane
  const int s = start[g], e = start[g + 1];
  float wA[8], wB[8];
  {
    const float4 a0 = ((const float4*)(logit_w + FD))[2 * sl];
    const float4 a1 = ((const float4*)(logit_w + FD))[2 * sl + 1];
    const float4 b0 = ((const float4*)(logit_w + 512 + FD))[2 * sl];
    const float4 b1 = ((const float4*)(logit_w + 512 + FD))[2 * sl + 1];
    wA[0]=a0.x; wA[1]=a0.y; wA[2]=a0.z; wA[3]=a0.w;
    wA[4]=a1.x; wA[5]=a1.y; wA[6]=a1.z; wA[7]=a1.w;
    wB[0]=b0.x; wB[1]=b0.y; wB[2]=b0.z; wB[3]=b0.w;
    wB[4]=b1.x; wB[5]=b1.y; wB[6]=b1.z; wB[7]=b1.w;
  }
  float ac[8];
#pragma unroll
  for (int j = 0; j < 8; ++j) ac[j] = 0.f;
  const float4* nfv = (const float4*)nf;
  int v = s + h;
  for (; v + 8 < e; v += 16) {                    // rows v and v+8 in flight
    const float4 x0 = nfv[(size_t)v * 64 + 2 * sl];
    const float4 x1 = nfv[(size_t)v * 64 + 2 * sl + 1];
    const float4 y0 = nfv[(size_t)(v + 8) * 64 + 2 * sl];
    const float4 y1 = nfv[(size_t)(v + 8) * 64 + 2 * sl + 1];
    uint4 u0, u1;
    u0.x = pkbf(x0.x, x0.y); u0.y = pkbf(x0.z, x0.w);
    u0.z = pkbf(x1.x, x1.y); u0.w = pkbf(x1.z, x1.w);
    ((uint4*)(nbf + (size_t)v * FD))[sl] = u0;
    u1.x = pkbf(y0.x, y0.y); u1.y = pkbf(y0.z, y0.w);
    u1.z = pkbf(y1.x, y1.y); u1.w = pkbf(y1.z, y1.w);
    ((uint4*)(nbf + (size_t)(v + 8) * FD))[sl] = u1;
    ac[0] += x0.x + y0.x; ac[1] += x0.y + y0.y;
    ac[2] += x0.z + y0.z; ac[3] += x0.w + y0.w;
    ac[4] += x1.x + y1.x; ac[5] += x1.y + y1.y;
    ac[6] += x1.z + y1.z; ac[7] += x1.w + y1.w;
    float dA0 = dot8(x0, x1, wA), dB0 = dot8(x0, x1, wB);
    float dA1 = dot8(y0, y1, wA), dB1 = dot8(y0, y1, wB);
#pragma unroll
    for (int off = 1; off < 32; off <<= 1) {      // 4 interleaved butterflies
      dA0 += __shfl_xor(dA0, off, 64); dB0 += __shfl_xor(dB0, off, 64);
      dA1 += __shfl_xor(dA1, off, 64); dB1 += __shfl_xor(dB1, off, 64);
    }
    if (sl == 0) {
      d0[v] = dA0; d1[v] = dB0;
      d0[v + 8] = dA1; d1[v + 8] = dB1;
    }
  }
  for (; v < e; v += 8) {
    const float4 x0 = nfv[(size_t)v * 64 + 2 * sl];
    const float4 x1 = nfv[(size_t)v * 64 + 2 * sl + 1];
    uint4 u0;
    u0.x = pkbf(x0.x, x0.y); u0.y = pkbf(x0.z, x0.w);
    u0.z = pkbf(x1.x, x1.y); u0.w = pkbf(x1.z, x1.w);
    ((uint4*)(nbf + (size_t)v * FD))[sl] = u0;
    ac[0] += x0.x; ac[1] += x0.y; ac[2] += x0.z; ac[3] += x0.w;
    ac[4] += x1.x; ac[5] += x1.y; ac[6] += x1.z; ac[7] += x1.w;
    float dA0 = dot8(x0, x1, wA), dB0 = dot8(x0, x1, wB);
#pragma unroll
    for (int off = 1; off < 32; off <<= 1) {
      dA0 += __shfl_xor(dA0, off, 64); dB0 += __shfl_xor(dB0, off, 64);
    }
    if (sl == 0) { d0[v] = dA0; d1[v] = dB0; }
  }
  ((float4*)&redf[h][sl * 8])[0] = make_float4(ac[0], ac[1], ac[2], ac[3]);
  ((float4*)&redf[h][sl * 8])[1] = make_float4(ac[4], ac[5], ac[6], ac[7]);
  __syncthreads();
  float sum = 0.f;
#pragma unroll
  for (int j = 0; j < 8; ++j) sum += redf[j][tid];
  gf[(size_t)g * FD + tid] = sum;
}

// ---- K2: time loop. GP=8 graphs/block, 512 blocks -> 2 blocks/CU.
// Wave per graph; GRU fused into gate-GEMM epilogue (no gi/gh buffers).
__global__ __launch_bounds__(SB, 4) void k_steps(
    const int* __restrict__ start, const float* __restrict__ logit_w,
    const float* __restrict__ logit_b, const float* __restrict__ proj_b,
    const float* __restrict__ b_ih, const float* __restrict__ b_hh,
    const u16* __restrict__ nbf, const float* __restrict__ d0,
    const float* __restrict__ d1, float* __restrict__ gf_out,
    const u16* __restrict__ wihbf, const u16* __restrict__ whhbf,
    const u16* __restrict__ whhlo, const u16* __restrict__ pwtbf) {
  __shared__ __align__(16) float gf_s[GP][FD];     // 8K: h lives here all kernel
  __shared__ __align__(16) float ew[EWCAP];        // 6K: softmax weights
  __shared__ __align__(16) u16 wns_s[16 * RS];     // 8.4K each; rows 8..15 zero pad
  __shared__ __align__(16) u16 ctx_s[16 * RS];
  __shared__ __align__(16) u16 hhi_s[16 * RS];
  __shared__ __align__(16) u16 hlo_s[16 * RS];

  const int b = blockIdx.x, tid = threadIdx.x;
  const int wv = tid >> 6, lane = tid & 63;        // 8 waves, wave wv owns graph g0+wv
  const int half = lane >> 5, sl = lane & 31;      // two 32-lane halves per wave
  const int g0 = b * GP;
  const int g = g0 + wv;
  const int vs = start[g0];
  const int s = start[g], e = start[g + 1];

  // zero MFMA A-operand pad rows 8..15 + load h into LDS
  for (int i = tid; i < 8 * RS; i += SB) {
    wns_s[8 * RS + i] = 0;
    hhi_s[8 * RS + i] = 0; hlo_s[8 * RS + i] = 0;
  }
  for (int i = tid; i < GP * FD; i += SB)
    gf_s[i >> 8][i & 255] = gf_out[(size_t)g0 * FD + i];
  __syncthreads();

  for (int t = 0; t < TSTEPS; ++t) {
    // ---- (A) h -> bf16 hi/lo in LDS
    for (int i = tid; i < GP * FD; i += SB) {
      const float x = gf_s[i >> 8][i & 255];
      const u16 hb = f2bf(x);
      hhi_s[(i >> 8) * RS + (i & 255)] = hb;
      hlo_s[(i >> 8) * RS + (i & 255)] = f2bf(x - bf2f(hb));
    }
    // ---- (B) softmax weights (full wave) + wsum stream -> wns_s
    {
      const float lb = logit_b[t];
      const float* dt = t ? d1 : d0;
      const float4 h4 = ((const float4*)&gf_s[wv][0])[lane];
      const float4 w4 = ((const float4*)(logit_w + (size_t)t * 512))[lane];
      float c = fmaf(fmaxf(h4.x, 0.f), w4.x, fmaf(fmaxf(h4.y, 0.f), w4.y,
                fmaf(fmaxf(h4.z, 0.f), w4.z, fmaxf(h4.w, 0.f) * w4.w)));
#pragma unroll
      for (int off = 1; off < 64; off <<= 1) c += __shfl_xor(c, off, 64);
      float m = -1e30f;
      for (int v2 = s + lane; v2 < e; v2 += 64) {
        const float z = softplus2(c + dt[v2] + lb);
        ew[v2 - vs] = z;
        m = fmaxf(m, z);
      }
#pragma unroll
      for (int off = 1; off < 64; off <<= 1) m = fmaxf(m, __shfl_xor(m, off, 64));
      float ls = 0.f;
      for (int v2 = s + lane; v2 < e; v2 += 64) {
        const float ez = __expf(ew[v2 - vs] - m);
        ew[v2 - vs] = ez;
        ls += ez;
      }
#pragma unroll
      for (int off = 1; off < 64; off <<= 1) ls += __shfl_xor(ls, off, 64);
      const float inv = (e > s) ? 1.0f / ls : 0.f;
      for (int v2 = s + lane; v2 < e; v2 += 64) ew[v2 - vs] *= inv;
      // weighted sum: halves take alternating rows, 4 rows in flight per half
      float acc[8];
#pragma unroll
      for (int j = 0; j < 8; ++j) acc[j] = 0.f;
      int v = s + half;
      for (; v + 6 < e; v += 8) {
        const uint4 u0 = ((const uint4*)(nbf + (size_t)v * FD))[sl];
        const uint4 u1 = ((const uint4*)(nbf + (size_t)(v + 2) * FD))[sl];
        const uint4 u2 = ((const uint4*)(nbf + (size_t)(v + 4) * FD))[sl];
        const uint4 u3 = ((const uint4*)(nbf + (size_t)(v + 6) * FD))[sl];
        const float a0 = ew[v - vs], a1 = ew[v + 2 - vs];
        const float a2 = ew[v + 4 - vs], a3 = ew[v + 6 - vs];
        acc[0] = fmaf(a0, bf2f((u16)(u0.x & 0xffff)), acc[0]);
        acc[1] = fmaf(a0, bf2f((u16)(u0.x >> 16)),    acc[1]);
        acc[2] = fmaf(a0, bf2f((u16)(u0.y & 0xffff)), acc[2]);
        acc[3] = fmaf(a0, bf2f((u16)(u0.y >> 16)),    acc[3]);
        acc[4] = fmaf(a0, bf2f((u16)(u0.z & 0xffff)), acc[4]);
        acc[5] = fmaf(a0, bf2f((u16)(u0.z >> 16)),    acc[5]);
        acc[6] = fmaf(a0, bf2f((u16)(u0.w & 0xffff)), acc[6]);
        acc[7] = fmaf(a0, bf2f((u16)(u0.w >> 16)),    acc[7]);
        acc[0] = fmaf(a1, bf2f((u16)(u1.x & 0xffff)), acc[0]);
        acc[1] = fmaf(a1, bf2f((u16)(u1.x >> 16)),    acc[1]);
        acc[2] = fmaf(a1, bf2f((u16)(u1.y & 0xffff)), acc[2]);
        acc[3] = fmaf(a1, bf2f((u16)(u1.y >> 16)),    acc[3]);
        acc[4] = fmaf(a1, bf2f((u16)(u1.z & 0xffff)), acc[4]);
        acc[5] = fmaf(a1, bf2f((u16)(u1.z >> 16)),    acc[5]);
        acc[6] = fmaf(a1, bf2f((u16)(u1.w & 0xffff)), acc[6]);
        acc[7] = fmaf(a1, bf2f((u16)(u1.w >> 16)),    acc[7]);
        acc[0] = fmaf(a2, bf2f((u16)(u2.x & 0xffff)), acc[0]);
        acc[1] = fmaf(a2, bf2f((u16)(u2.x >> 16)),    acc[1]);
        acc[2] = fmaf(a2, bf2f((u16)(u2.y & 0xffff)), acc[2]);
        acc[3] = fmaf(a2, bf2f((u16)(u2.y >> 16)),    acc[3]);
        acc[4] = fmaf(a2, bf2f((u16)(u2.z & 0xffff)), acc[4]);
        acc[5] = fmaf(a2, bf2f((u16)(u2.z >> 16)),    acc[5]);
        acc[6] = fmaf(a2, bf2f((u16)(u2.w & 0xffff)), acc[6]);
        acc[7] = fmaf(a2, bf2f((u16)(u2.w >> 16)),    acc[7]);
        acc[0] = fmaf(a3, bf2f((u16)(u3.x & 0xffff)), acc[0]);
        acc[1] = fmaf(a3, bf2f((u16)(u3.x >> 16)),    acc[1]);
        acc[2] = fmaf(a3, bf2f((u16)(u3.y & 0xffff)), acc[2]);
        acc[3] = fmaf(a3, bf2f((u16)(u3.y >> 16)),    acc[3]);
        acc[4] = fmaf(a3, bf2f((u16)(u3.z & 0xffff)), acc[4]);
        acc[5] = fmaf(a3, bf2f((u16)(u3.z >> 16)),    acc[5]);
        acc[6] = fmaf(a3, bf2f((u16)(u3.w & 0xffff)), acc[6]);
        acc[7] = fmaf(a3, bf2f((u16)(u3.w >> 16)),    acc[7]);
      }
      for (; v < e; v += 2) {
        const uint4 u0 = ((const uint4*)(nbf + (size_t)v * FD))[sl];
        const float a0 = ew[v - vs];
        acc[0] = fmaf(a0, bf2f((u16)(u0.x & 0xffff)), acc[0]);
        acc[1] = fmaf(a0, bf2f((u16)(u0.x >> 16)),    acc[1]);
        acc[2] = fmaf(a0, bf2f((u16)(u0.y & 0xffff)), acc[2]);
        acc[3] = fmaf(a0, bf2f((u16)(u0.y >> 16)),    acc[3]);
        acc[4] = fmaf(a0, bf2f((u16)(u0.z & 0xffff)), acc[4]);
        acc[5] = fmaf(a0, bf2f((u16)(u0.z >> 16)),    acc[5]);
        acc[6] = fmaf(a0, bf2f((u16)(u0.w & 0xffff)), acc[6]);
        acc[7] = fmaf(a0, bf2f((u16)(u0.w >> 16)),    acc[7]);
      }
#pragma unroll
      for (int j = 0; j < 8; ++j) acc[j] += __shfl_xor(acc[j], 32, 64);
      if (half == 0) {
        uint4 w;
        w.x = pkbf(acc[0], acc[1]); w.y = pkbf(acc[2], acc[3]);
        w.z = pkbf(acc[4], acc[5]); w.w = pkbf(acc[6], acc[7]);
        *(uint4*)(wns_s + wv * RS + sl * 8) = w;
      }
    }
    __syncthreads();
    // ---- (C) ctx = elu(wns @ proj_w^T + proj_b); 16 tiles, 2/wave
    {
      const int r = lane & 15, q = lane >> 4;
      const u16* xp = wns_s + r * RS + q * 8;
#pragma unroll
      for (int jj = 0; jj < 2; ++jj) {
        const int nt = wv * 2 + jj;
        const u16* wp = pwtbf + (size_t)t * FD * FD + (size_t)(nt * 16 + r) * FD + q * 8;
        f32x4 a4 = {0.f, 0.f, 0.f, 0.f};
#pragma unroll
        for (int kt = 0; kt < 8; ++kt) {
          const short8 av = *(const short8*)(xp + kt * 32);
          const short8 bv = *(const short8*)(wp + kt * 32);
          a4 = __builtin_amdgcn_mfma_f32_16x16x32_bf16(av, bv, a4, 0, 0, 0);
        }
        const int gcol = nt * 16 + r;
        const float bs = proj_b[t * FD + gcol];
#pragma unroll
        for (int i = 0; i < 4; ++i) {
          float vv = a4[i] + bs;
          vv = (vv > 0.0f) ? vv : expm1f(vv);
          ctx_s[(q * 4 + i) * RS + gcol] = f2bf(vv);
        }
      }
    }
    __syncthreads();
    // ---- (D) gate GEMMs + GRU fused in epilogue; wave owns 2 col-tiles of 16
    {
      const int r = lane & 15, q = lane >> 4;
      const u16* xi = ctx_s + r * RS + q * 8;
      const u16* xh = hhi_s + r * RS + q * 8;
      const u16* xl = hlo_s + r * RS + q * 8;
      const u16* wih_t = wihbf + (size_t)t * 768 * FD;
      const u16* whh_t = whhbf + (size_t)t * 768 * FD;
      const u16* whl_t = whhlo + (size_t)t * 768 * FD;
      auto gpair = [&](const u16* wi, const u16* wh, const u16* wl,
                       f32x4& ai, f32x4& ah) {
#pragma unroll
        for (int kt = 0; kt < 8; ++kt) {
          const short8 aiv = *(const short8*)(xi + kt * 32);
          const short8 bi  = *(const short8*)(wi + kt * 32);
          ai = __builtin_amdgcn_mfma_f32_16x16x32_bf16(aiv, bi, ai, 0, 0, 0);
          const short8 xhh = *(const short8*)(xh + kt * 32);
          const short8 xll = *(const short8*)(xl + kt * 32);
          const short8 bh  = *(const short8*)(wh + kt * 32);
          const short8 bl  = *(const short8*)(wl + kt * 32);
          ah = __builtin_amdgcn_mfma_f32_16x16x32_bf16(xhh, bh, ah, 0, 0, 0);
          ah = __builtin_amdgcn_mfma_f32_16x16x32_bf16(xll, bh, ah, 0, 0, 0);
          ah = __builtin_amdgcn_mfma_f32_16x16x32_bf16(xhh, bl, ah, 0, 0, 0);
        }
      };
#pragma unroll
      for (int jj = 0; jj < 2; ++jj) {
        const int col = (wv * 2 + jj) * 16 + r;   // 0..255
        float rr[4], zz[4];
        {
          f32x4 ai = {0.f,0.f,0.f,0.f}, ah = {0.f,0.f,0.f,0.f};
          gpair(wih_t + (size_t)col * FD + q * 8,
                whh_t + (size_t)col * FD + q * 8,
                whl_t + (size_t)col * FD + q * 8, ai, ah);
          const float bi_ = b_ih[t * 768 + col], bh_ = b_hh[t * 768 + col];
#pragma unroll
          for (int i = 0; i < 4; ++i)
            rr[i] = 1.f / (1.f + __expf(-(ai[i] + bi_ + ah[i] + bh_)));
        }
        {
          f32x4 ai = {0.f,0.f,0.f,0.f}, ah = {0.f,0.f,0.f,0.f};
          gpair(wih_t + (size_t)(256 + col) * FD + q * 8,
                whh_t + (size_t)(256 + col) * FD + q * 8,
                whl_t + (size_t)(256 + col) * FD + q * 8, ai, ah);
          const float bi_ = b_ih[t * 768 + 256 + col], bh_ = b_hh[t * 768 + 256 + col];
#pragma unroll
          for (int i = 0; i < 4; ++i)
            zz[i] = 1.f / (1.f + __expf(-(ai[i] + bi_ + ah[i] + bh_)));
        }
        {
          f32x4 ai = {0.f,0.f,0.f,0.f}, ah = {0.f,0.f,0.f,0.f};
          gpair(wih_t + (size_t)(512 + col) * FD + q * 8,
                whh_t + (size_t)(512 + col) * FD + q * 8,
                whl_t + (size_t)(512 + col) * FD + q * 8, ai, ah);
          const float bi_ = b_ih[t * 768 + 512 + col], bh_ = b_hh[t * 768 + 512 + col];
          if (q < 2) {                            // rows 0..7 are real graphs
#pragma unroll
            for (int i = 0; i < 4; ++i) {
              const int row = q * 4 + i;
              const float nn = tanhf(ai[i] + bi_ + rr[i] * (ah[i] + bh_));
              const float hold = gf_s[row][col];
              gf_s[row][col] = (1.f - zz[i]) * nn + zz[i] * hold;
            }
          }
        }
      }
    }
    __syncthreads();
  }

  // ---- final store: gf_s -> global
  ((float4*)(gf_out + (size_t)g0 * FD))[tid] = ((const float4*)gf_s)[tid];
}

extern "C" void kernel_launch(void* const* d_in, const int* in_sizes, int n_in,
                              void* d_out, int out_size, void* d_ws, size_t ws_size,
                              hipStream_t stream) {
  const float* node    = (const float*)d_in[0];
  const int*   seg     = (const int*)d_in[1];
  const float* logit_w = (const float*)d_in[3];
  const float* logit_b = (const float*)d_in[4];
  const float* proj_w  = (const float*)d_in[5];
  const float* proj_b  = (const float*)d_in[6];
  const float* w_ih    = (const float*)d_in[7];
  const float* w_hh    = (const float*)d_in[8];
  const float* b_ih    = (const float*)d_in[9];
  const float* b_hh    = (const float*)d_in[10];
  float* gfeats = (float*)d_out;

  char* p = (char*)d_ws;
  int* start   = (int*)p;   p += (((NGRAPH + 1) * sizeof(int)) + 255) & ~(size_t)255;
  u16* nbf     = (u16*)p;   p += (size_t)V_NODES * FD * 2;
  float* d0    = (float*)p; p += (size_t)V_NODES * 4;
  float* d1    = (float*)p; p += (size_t)V_NODES * 4;
  u16* wihbf   = (u16*)p;   p += (size_t)TSTEPS * 768 * FD * 2;
  u16* whhbf   = (u16*)p;   p += (size_t)TSTEPS * 768 * FD * 2;
  u16* whhlo   = (u16*)p;   p += (size_t)TSTEPS * 768 * FD * 2;
  u16* pwtbf   = (u16*)p;   p += (size_t)TSTEPS * FD * FD * 2;
  (void)ws_size; (void)in_sizes; (void)n_in; (void)out_size;

  k_prep<<<dim3(V_NODES / 256), dim3(256), 0, stream>>>(
      seg, w_ih, w_hh, proj_w, start, wihbf, whhbf, whhlo, pwtbf);
  k_pass1<<<dim3(NGRAPH), dim3(256), 0, stream>>>(
      node, start, logit_w, gfeats, nbf, d0, d1);
  k_steps<<<dim3(NGRAPH / GP), dim3(SB), 0, stream>>>(
      start, logit_w, logit_b, proj_b, b_ih, b_hh, nbf, d0, d1,
      gfeats, wihbf, whhbf, whhlo, pwtbf);
}

// Round 3
// 537.088 us; speedup vs baseline: 1.2688x; 1.2688x over previous
//
#include <hip/hip_runtime.h>
#include <hip/hip_bf16.h>
#include <math.h>

#define V_NODES 262144
#define NGRAPH  4096
#define FD      256
#define TSTEPS  2
#define GP      16     // graphs per k_steps block (one wave per graph)
#define SB      1024   // k_steps block size: 16 waves -> 16 waves/CU at 1 block/CU
#define RS      264    // padded LDS row stride (u16) — 528B = 33*16B, +4-bank skew
#define EWCAP   2560   // max nodes per GP-graph block (mean 1024, sigma ~32)

typedef unsigned short u16;
typedef __attribute__((ext_vector_type(8))) short short8;
typedef __attribute__((ext_vector_type(4))) float f32x4;

__device__ __forceinline__ float bf2f(u16 u) {
  union { unsigned int i; float f; } x; x.i = ((unsigned int)u) << 16; return x.f;
}
__device__ __forceinline__ u16 f2bf(float f) {
  union { unsigned int i; float f; } x; x.f = f;
  unsigned int r = x.i + 0x7FFFu + ((x.i >> 16) & 1u);
  return (u16)(r >> 16);
}
__device__ __forceinline__ unsigned int pkbf(float a, float b) {
  return (unsigned int)f2bf(a) | ((unsigned int)f2bf(b) << 16);
}
__device__ __forceinline__ float softplus2(float x) {
  return fmaxf(x, 0.0f) + log1pf(__expf(-fabsf(x))) - 0.69314718056f;
}
__device__ __forceinline__ float dot8(const float4 x0, const float4 x1, const float* w) {
  float d = fmaf(x0.x, w[0], fmaf(x0.y, w[1], fmaf(x0.z, w[2], x0.w * w[3])));
  return fmaf(x1.x, w[4], fmaf(x1.y, w[5], fmaf(x1.z, w[6], fmaf(x1.w, w[7], d))));
}

// ---- K0: bounds + weight conversions + proj transpose (one launch)
__global__ __launch_bounds__(256) void k_prep(
    const int* __restrict__ seg, const float* __restrict__ w_ih,
    const float* __restrict__ w_hh, const float* __restrict__ proj_w,
    int* __restrict__ start, u16* __restrict__ wihbf, u16* __restrict__ whhbf,
    u16* __restrict__ whhlo, u16* __restrict__ pwtbf) {
  __shared__ float tl[32][33];
  const int b = blockIdx.x, tid = threadIdx.x;
  const int gtid = b * 256 + tid;  // 0..262143
  {
    const int v = gtid;
    const int s = seg[v];
    if (v == 0) {
      for (int g = 0; g <= s; ++g) start[g] = 0;
    } else {
      const int p = seg[v - 1];
      for (int g = p + 1; g <= s; ++g) start[g] = v;
    }
    if (v == V_NODES - 1)
      for (int g = s + 1; g <= NGRAPH; ++g) start[g] = V_NODES;
  }
  {
    const int nchunk = TSTEPS * 768 * FD / 4;  // 98304
    if (gtid < nchunk) {
      const float4 x = ((const float4*)w_ih)[gtid];
      uint2 u; u.x = pkbf(x.x, x.y); u.y = pkbf(x.z, x.w);
      ((uint2*)wihbf)[gtid] = u;
      const float4 y = ((const float4*)w_hh)[gtid];
      const u16 h0 = f2bf(y.x), h1 = f2bf(y.y), h2 = f2bf(y.z), h3 = f2bf(y.w);
      uint2 hi_, lo_;
      hi_.x = (unsigned)h0 | ((unsigned)h1 << 16);
      hi_.y = (unsigned)h2 | ((unsigned)h3 << 16);
      lo_.x = pkbf(y.x - bf2f(h0), y.y - bf2f(h1));
      lo_.y = pkbf(y.z - bf2f(h2), y.w - bf2f(h3));
      ((uint2*)whhbf)[gtid] = hi_;
      ((uint2*)whhlo)[gtid] = lo_;
    }
  }
  if (b < 2 * 64) {  // proj_w [k][n] -> bf16 [n][k]
    const int t = b >> 6, tile = b & 63, bx = tile & 7, by = tile >> 3;
    const int tx = tid & 31, ty = tid >> 5;  // 32 x 8
    const float* S = proj_w + (size_t)t * FD * FD;
    u16* D = pwtbf + (size_t)t * FD * FD;
#pragma unroll
    for (int i = 0; i < 32; i += 8)
      tl[ty + i][tx] = S[(size_t)(by * 32 + ty + i) * FD + bx * 32 + tx];
    __syncthreads();
#pragma unroll
    for (int i = 0; i < 32; i += 8)
      D[(size_t)(bx * 32 + ty + i) * FD + by * 32 + tx] = f2bf(tl[tx][ty + i]);
  }
}

// ---- K1: block per graph (4096 blocks): segsum -> gf, bf16 copy, logit dots.
// 4 rows in flight per half-wave; 8 interleaved shfl butterflies.
__global__ __launch_bounds__(256) void k_pass1(
    const float* __restrict__ nf, const int* __restrict__ start,
    const float* __restrict__ logit_w, float* __restrict__ gf,
    u16* __restrict__ nbf, float* __restrict__ d0, float* __restrict__ d1) {
  __shared__ __align__(16) float redf[8][FD];
  const int g = blockIdx.x, tid = threadIdx.x;
  const int h = tid >> 5, sl = tid & 31;  // 8 half-waves, 8 feats/lane
  const int s = start[g], e = start[g + 1];
  float wA[8], wB[8];
  {
    const float4 a0 = ((const float4*)(logit_w + FD))[2 * sl];
    const float4 a1 = ((const float4*)(logit_w + FD))[2 * sl + 1];
    const float4 b0 = ((const float4*)(logit_w + 512 + FD))[2 * sl];
    const float4 b1 = ((const float4*)(logit_w + 512 + FD))[2 * sl + 1];
    wA[0]=a0.x; wA[1]=a0.y; wA[2]=a0.z; wA[3]=a0.w;
    wA[4]=a1.x; wA[5]=a1.y; wA[6]=a1.z; wA[7]=a1.w;
    wB[0]=b0.x; wB[1]=b0.y; wB[2]=b0.z; wB[3]=b0.w;
    wB[4]=b1.x; wB[5]=b1.y; wB[6]=b1.z; wB[7]=b1.w;
  }
  float ac[8];
#pragma unroll
  for (int j = 0; j < 8; ++j) ac[j] = 0.f;
  const float4* nfv = (const float4*)nf;
  int v = s + h;
  for (; v + 24 < e; v += 32) {                   // rows v, v+8, v+16, v+24 in flight
    float4 x0[4], x1[4];
#pragma unroll
    for (int r = 0; r < 4; ++r) {
      x0[r] = nfv[(size_t)(v + 8 * r) * 64 + 2 * sl];
      x1[r] = nfv[(size_t)(v + 8 * r) * 64 + 2 * sl + 1];
    }
#pragma unroll
    for (int r = 0; r < 4; ++r) {
      uint4 u;
      u.x = pkbf(x0[r].x, x0[r].y); u.y = pkbf(x0[r].z, x0[r].w);
      u.z = pkbf(x1[r].x, x1[r].y); u.w = pkbf(x1[r].z, x1[r].w);
      ((uint4*)(nbf + (size_t)(v + 8 * r) * FD))[sl] = u;
      ac[0] += x0[r].x; ac[1] += x0[r].y; ac[2] += x0[r].z; ac[3] += x0[r].w;
      ac[4] += x1[r].x; ac[5] += x1[r].y; ac[6] += x1[r].z; ac[7] += x1[r].w;
    }
    float dA[4], dB[4];
#pragma unroll
    for (int r = 0; r < 4; ++r) {
      dA[r] = dot8(x0[r], x1[r], wA);
      dB[r] = dot8(x0[r], x1[r], wB);
    }
#pragma unroll
    for (int off = 1; off < 32; off <<= 1) {      // 8 interleaved butterflies
#pragma unroll
      for (int r = 0; r < 4; ++r) {
        dA[r] += __shfl_xor(dA[r], off, 64);
        dB[r] += __shfl_xor(dB[r], off, 64);
      }
    }
    if (sl == 0) {
#pragma unroll
      for (int r = 0; r < 4; ++r) { d0[v + 8 * r] = dA[r]; d1[v + 8 * r] = dB[r]; }
    }
  }
  for (; v < e; v += 8) {
    const float4 x0 = nfv[(size_t)v * 64 + 2 * sl];
    const float4 x1 = nfv[(size_t)v * 64 + 2 * sl + 1];
    uint4 u0;
    u0.x = pkbf(x0.x, x0.y); u0.y = pkbf(x0.z, x0.w);
    u0.z = pkbf(x1.x, x1.y); u0.w = pkbf(x1.z, x1.w);
    ((uint4*)(nbf + (size_t)v * FD))[sl] = u0;
    ac[0] += x0.x; ac[1] += x0.y; ac[2] += x0.z; ac[3] += x0.w;
    ac[4] += x1.x; ac[5] += x1.y; ac[6] += x1.z; ac[7] += x1.w;
    float dA0 = dot8(x0, x1, wA), dB0 = dot8(x0, x1, wB);
#pragma unroll
    for (int off = 1; off < 32; off <<= 1) {
      dA0 += __shfl_xor(dA0, off, 64); dB0 += __shfl_xor(dB0, off, 64);
    }
    if (sl == 0) { d0[v] = dA0; d1[v] = dB0; }
  }
  ((float4*)&redf[h][sl * 8])[0] = make_float4(ac[0], ac[1], ac[2], ac[3]);
  ((float4*)&redf[h][sl * 8])[1] = make_float4(ac[4], ac[5], ac[6], ac[7]);
  __syncthreads();
  float sum = 0.f;
#pragma unroll
  for (int j = 0; j < 8; ++j) sum += redf[j][tid];
  gf[(size_t)g * FD + tid] = sum;
}

// ---- K2: time loop. GP=16 graphs/block, 256 blocks, 16 waves/block.
// One wave per graph; full 16-row MFMA tiles; GRU fused in gate-GEMM epilogue.
__global__ __launch_bounds__(SB, 4) void k_steps(
    const int* __restrict__ start, const float* __restrict__ logit_w,
    const float* __restrict__ logit_b, const float* __restrict__ proj_b,
    const float* __restrict__ b_ih, const float* __restrict__ b_hh,
    const u16* __restrict__ nbf, const float* __restrict__ d0,
    const float* __restrict__ d1, float* __restrict__ gf_out,
    const u16* __restrict__ wihbf, const u16* __restrict__ whhbf,
    const u16* __restrict__ whhlo, const u16* __restrict__ pwtbf) {
  __shared__ __align__(16) float gf_s[GP][FD];     // 16K: h lives here all kernel
  __shared__ __align__(16) float ew[EWCAP];        // 10K: softmax weights
  __shared__ __align__(16) u16 wns_s[GP * RS];     // 8448B each; all 16 rows real
  __shared__ __align__(16) u16 ctx_s[GP * RS];
  __shared__ __align__(16) u16 hhi_s[GP * RS];
  __shared__ __align__(16) u16 hlo_s[GP * RS];

  const int b = blockIdx.x, tid = threadIdx.x;
  const int wv = tid >> 6, lane = tid & 63;        // 16 waves, wave wv owns graph g0+wv
  const int half = lane >> 5, sl = lane & 31;      // two 32-lane halves per wave
  const int g0 = b * GP;
  const int g = g0 + wv;
  const int vs = start[g0];
  const int s = start[g], e = start[g + 1];

  // load h into LDS (one float4 per thread: GP*FD/4 == SB)
  ((float4*)gf_s)[tid] = ((const float4*)(gf_out + (size_t)g0 * FD))[tid];
  __syncthreads();

  for (int t = 0; t < TSTEPS; ++t) {
    // ---- (A) h -> bf16 hi/lo in LDS
    for (int i = tid; i < GP * FD; i += SB) {
      const float x = gf_s[i >> 8][i & 255];
      const u16 hb = f2bf(x);
      hhi_s[(i >> 8) * RS + (i & 255)] = hb;
      hlo_s[(i >> 8) * RS + (i & 255)] = f2bf(x - bf2f(hb));
    }
    // ---- (B) softmax weights (full wave) + wsum stream -> wns_s
    {
      const float lb = logit_b[t];
      const float* dt = t ? d1 : d0;
      const float4 h4 = ((const float4*)&gf_s[wv][0])[lane];
      const float4 w4 = ((const float4*)(logit_w + (size_t)t * 512))[lane];
      float c = fmaf(fmaxf(h4.x, 0.f), w4.x, fmaf(fmaxf(h4.y, 0.f), w4.y,
                fmaf(fmaxf(h4.z, 0.f), w4.z, fmaxf(h4.w, 0.f) * w4.w)));
#pragma unroll
      for (int off = 1; off < 64; off <<= 1) c += __shfl_xor(c, off, 64);
      float m = -1e30f;
      for (int v2 = s + lane; v2 < e; v2 += 64) {
        const float z = softplus2(c + dt[v2] + lb);
        ew[v2 - vs] = z;
        m = fmaxf(m, z);
      }
#pragma unroll
      for (int off = 1; off < 64; off <<= 1) m = fmaxf(m, __shfl_xor(m, off, 64));
      float ls = 0.f;
      for (int v2 = s + lane; v2 < e; v2 += 64) {
        const float ez = __expf(ew[v2 - vs] - m);
        ew[v2 - vs] = ez;
        ls += ez;
      }
#pragma unroll
      for (int off = 1; off < 64; off <<= 1) ls += __shfl_xor(ls, off, 64);
      const float inv = (e > s) ? 1.0f / ls : 0.f;
      for (int v2 = s + lane; v2 < e; v2 += 64) ew[v2 - vs] *= inv;
      // weighted sum: halves take alternating rows, 8 rows in flight per half
      float acc[8];
#pragma unroll
      for (int j = 0; j < 8; ++j) acc[j] = 0.f;
      int v = s + half;
      for (; v + 14 < e; v += 16) {
        uint4 u[8];
#pragma unroll
        for (int r = 0; r < 8; ++r)
          u[r] = ((const uint4*)(nbf + (size_t)(v + 2 * r) * FD))[sl];
#pragma unroll
        for (int r = 0; r < 8; ++r) {
          const float a = ew[v + 2 * r - vs];
          acc[0] = fmaf(a, bf2f((u16)(u[r].x & 0xffff)), acc[0]);
          acc[1] = fmaf(a, bf2f((u16)(u[r].x >> 16)),    acc[1]);
          acc[2] = fmaf(a, bf2f((u16)(u[r].y & 0xffff)), acc[2]);
          acc[3] = fmaf(a, bf2f((u16)(u[r].y >> 16)),    acc[3]);
          acc[4] = fmaf(a, bf2f((u16)(u[r].z & 0xffff)), acc[4]);
          acc[5] = fmaf(a, bf2f((u16)(u[r].z >> 16)),    acc[5]);
          acc[6] = fmaf(a, bf2f((u16)(u[r].w & 0xffff)), acc[6]);
          acc[7] = fmaf(a, bf2f((u16)(u[r].w >> 16)),    acc[7]);
        }
      }
      for (; v < e; v += 2) {
        const uint4 u0 = ((const uint4*)(nbf + (size_t)v * FD))[sl];
        const float a0 = ew[v - vs];
        acc[0] = fmaf(a0, bf2f((u16)(u0.x & 0xffff)), acc[0]);
        acc[1] = fmaf(a0, bf2f((u16)(u0.x >> 16)),    acc[1]);
        acc[2] = fmaf(a0, bf2f((u16)(u0.y & 0xffff)), acc[2]);
        acc[3] = fmaf(a0, bf2f((u16)(u0.y >> 16)),    acc[3]);
        acc[4] = fmaf(a0, bf2f((u16)(u0.z & 0xffff)), acc[4]);
        acc[5] = fmaf(a0, bf2f((u16)(u0.z >> 16)),    acc[5]);
        acc[6] = fmaf(a0, bf2f((u16)(u0.w & 0xffff)), acc[6]);
        acc[7] = fmaf(a0, bf2f((u16)(u0.w >> 16)),    acc[7]);
      }
#pragma unroll
      for (int j = 0; j < 8; ++j) acc[j] += __shfl_xor(acc[j], 32, 64);
      if (half == 0) {
        uint4 w;
        w.x = pkbf(acc[0], acc[1]); w.y = pkbf(acc[2], acc[3]);
        w.z = pkbf(acc[4], acc[5]); w.w = pkbf(acc[6], acc[7]);
        *(uint4*)(wns_s + wv * RS + sl * 8) = w;
      }
    }
    __syncthreads();
    // ---- (C) ctx = elu(wns @ proj_w^T + proj_b); 16 tiles, 1/wave
    {
      const int r = lane & 15, q = lane >> 4;
      const u16* xp = wns_s + r * RS + q * 8;
      const u16* wp = pwtbf + (size_t)t * FD * FD + (size_t)(wv * 16 + r) * FD + q * 8;
      f32x4 a4 = {0.f, 0.f, 0.f, 0.f};
#pragma unroll
      for (int kt = 0; kt < 8; ++kt) {
        const short8 av = *(const short8*)(xp + kt * 32);
        const short8 bv = *(const short8*)(wp + kt * 32);
        a4 = __builtin_amdgcn_mfma_f32_16x16x32_bf16(av, bv, a4, 0, 0, 0);
      }
      const int gcol = wv * 16 + r;
      const float bs = proj_b[t * FD + gcol];
#pragma unroll
      for (int i = 0; i < 4; ++i) {
        float vv = a4[i] + bs;
        vv = (vv > 0.0f) ? vv : expm1f(vv);
        ctx_s[(q * 4 + i) * RS + gcol] = f2bf(vv);
      }
    }
    __syncthreads();
    // ---- (D) gate GEMMs + GRU fused in epilogue; wave owns 1 col-tile of 16
    {
      const int r = lane & 15, q = lane >> 4;
      const u16* xi = ctx_s + r * RS + q * 8;
      const u16* xh = hhi_s + r * RS + q * 8;
      const u16* xl = hlo_s + r * RS + q * 8;
      const u16* wih_t = wihbf + (size_t)t * 768 * FD;
      const u16* whh_t = whhbf + (size_t)t * 768 * FD;
      const u16* whl_t = whhlo + (size_t)t * 768 * FD;
      auto gpair = [&](const u16* wi, const u16* wh, const u16* wl,
                       f32x4& ai, f32x4& ah) {
#pragma unroll
        for (int kt = 0; kt < 8; ++kt) {
          const short8 aiv = *(const short8*)(xi + kt * 32);
          const short8 bi  = *(const short8*)(wi + kt * 32);
          ai = __builtin_amdgcn_mfma_f32_16x16x32_bf16(aiv, bi, ai, 0, 0, 0);
          const short8 xhh = *(const short8*)(xh + kt * 32);
          const short8 xll = *(const short8*)(xl + kt * 32);
          const short8 bh  = *(const short8*)(wh + kt * 32);
          const short8 bl  = *(const short8*)(wl + kt * 32);
          ah = __builtin_amdgcn_mfma_f32_16x16x32_bf16(xhh, bh, ah, 0, 0, 0);
          ah = __builtin_amdgcn_mfma_f32_16x16x32_bf16(xll, bh, ah, 0, 0, 0);
          ah = __builtin_amdgcn_mfma_f32_16x16x32_bf16(xhh, bl, ah, 0, 0, 0);
        }
      };
      const int col = wv * 16 + r;                // 0..255
      float rr[4], zz[4];
      {
        f32x4 ai = {0.f,0.f,0.f,0.f}, ah = {0.f,0.f,0.f,0.f};
        gpair(wih_t + (size_t)col * FD + q * 8,
              whh_t + (size_t)col * FD + q * 8,
              whl_t + (size_t)col * FD + q * 8, ai, ah);
        const float bi_ = b_ih[t * 768 + col], bh_ = b_hh[t * 768 + col];
#pragma unroll
        for (int i = 0; i < 4; ++i)
          rr[i] = 1.f / (1.f + __expf(-(ai[i] + bi_ + ah[i] + bh_)));
      }
      {
        f32x4 ai = {0.f,0.f,0.f,0.f}, ah = {0.f,0.f,0.f,0.f};
        gpair(wih_t + (size_t)(256 + col) * FD + q * 8,
              whh_t + (size_t)(256 + col) * FD + q * 8,
              whl_t + (size_t)(256 + col) * FD + q * 8, ai, ah);
        const float bi_ = b_ih[t * 768 + 256 + col], bh_ = b_hh[t * 768 + 256 + col];
#pragma unroll
        for (int i = 0; i < 4; ++i)
          zz[i] = 1.f / (1.f + __expf(-(ai[i] + bi_ + ah[i] + bh_)));
      }
      {
        f32x4 ai = {0.f,0.f,0.f,0.f}, ah = {0.f,0.f,0.f,0.f};
        gpair(wih_t + (size_t)(512 + col) * FD + q * 8,
              whh_t + (size_t)(512 + col) * FD + q * 8,
              whl_t + (size_t)(512 + col) * FD + q * 8, ai, ah);
        const float bi_ = b_ih[t * 768 + 512 + col], bh_ = b_hh[t * 768 + 512 + col];
#pragma unroll
        for (int i = 0; i < 4; ++i) {
          const int row = q * 4 + i;              // all 16 rows are real graphs
          const float nn = tanhf(ai[i] + bi_ + rr[i] * (ah[i] + bh_));
          const float hold = gf_s[row][col];
          gf_s[row][col] = (1.f - zz[i]) * nn + zz[i] * hold;
        }
      }
    }
    __syncthreads();
  }

  // ---- final store: gf_s -> global (one float4 per thread)
  ((float4*)(gf_out + (size_t)g0 * FD))[tid] = ((const float4*)gf_s)[tid];
}

extern "C" void kernel_launch(void* const* d_in, const int* in_sizes, int n_in,
                              void* d_out, int out_size, void* d_ws, size_t ws_size,
                              hipStream_t stream) {
  const float* node    = (const float*)d_in[0];
  const int*   seg     = (const int*)d_in[1];
  const float* logit_w = (const float*)d_in[3];
  const float* logit_b = (const float*)d_in[4];
  const float* proj_w  = (const float*)d_in[5];
  const float* proj_b  = (const float*)d_in[6];
  const float* w_ih    = (const float*)d_in[7];
  const float* w_hh    = (const float*)d_in[8];
  const float* b_ih    = (const float*)d_in[9];
  const float* b_hh    = (const float*)d_in[10];
  float* gfeats = (float*)d_out;

  char* p = (char*)d_ws;
  int* start   = (int*)p;   p += (((NGRAPH + 1) * sizeof(int)) + 255) & ~(size_t)255;
  u16* nbf     = (u16*)p;   p += (size_t)V_NODES * FD * 2;
  float* d0    = (float*)p; p += (size_t)V_NODES * 4;
  float* d1    = (float*)p; p += (size_t)V_NODES * 4;
  u16* wihbf   = (u16*)p;   p += (size_t)TSTEPS * 768 * FD * 2;
  u16* whhbf   = (u16*)p;   p += (size_t)TSTEPS * 768 * FD * 2;
  u16* whhlo   = (u16*)p;   p += (size_t)TSTEPS * 768 * FD * 2;
  u16* pwtbf   = (u16*)p;   p += (size_t)TSTEPS * FD * FD * 2;
  (void)ws_size; (void)in_sizes; (void)n_in; (void)out_size;

  k_prep<<<dim3(V_NODES / 256), dim3(256), 0, stream>>>(
      seg, w_ih, w_hh, proj_w, start, wihbf, whhbf, whhlo, pwtbf);
  k_pass1<<<dim3(NGRAPH), dim3(256), 0, stream>>>(
      node, start, logit_w, gfeats, nbf, d0, d1);
  k_steps<<<dim3(NGRAPH / GP), dim3(SB), 0, stream>>>(
      start, logit_w, logit_b, proj_b, b_ih, b_hh, nbf, d0, d1,
      gfeats, wihbf, whhbf, whhlo, pwtbf);
}